// Round 20
// baseline (189.233 us; speedup 1.0000x reference)
//
#include <hip/hip_runtime.h>
#include <hip/hip_bf16.h>
#include <math.h>

typedef __attribute__((ext_vector_type(8))) short short8;
typedef __attribute__((ext_vector_type(4))) short s4;
typedef __attribute__((ext_vector_type(4))) float f32x4;

#define NJ 24

// ---- ws image: per-fragment 1KB blocks (64 lanes x 16B), lane-major ----
// W1image row 13 = b1 (bias-as-K: x[13]=1), row13 col77 = 1.0 (h[77] regenerator)
// W2image row 77 = b2
#define F1_J   7680
#define F2_OFF (NJ*F1_J)
#define F2_J   6144
#define FP_OFF (F2_OFF + NJ*F2_J)
#define IMG_SHORTS (FP_OFF + 36*512)        // 350208 shorts = 700416 B

// operand-swapped MFMA: A = weights [n][k], B = activations [k][batch]
#define MFMA(A,B,C) __builtin_amdgcn_mfma_f32_16x16x32_bf16((A),(B),(C),0,0,0)

// DFS order; 2-slot schedule (root prior in slot 1, consumed only at p=0)
__constant__ int ORD[24] = {0,1,4,7,10, 2,5,8,11, 3,6,9, 12,15, 13,16,18,20,22, 14,17,19,21,23};
__constant__ int PSL[24] = {1,0,1,1,1,  0,1,1,1,  0,0,0,  0,1,   0,1,1,1,1,    0,0,0,0,0};
__constant__ int SSL[24] = {0,1,1,1,-1, 1,1,1,-1, 0,0,0,  1,-1,  1,1,1,1,-1,   0,0,0,0,-1};

__device__ __forceinline__ short f2bf(float f) {
  union { float f; unsigned u; } v; v.f = f;
  unsigned r = v.u + 0x7FFFu + ((v.u >> 16) & 1u);
  return (short)(r >> 16);
}
__device__ __forceinline__ short sbf(float f) {
  __hip_bfloat16 h = __float2bfloat16(f);
  return *reinterpret_cast<short*>(&h);
}
__device__ __forceinline__ short8 pk8(f32x4 lo, f32x4 hi) {
  union { short8 s; unsigned u[4]; } r;
  asm("v_cvt_pk_bf16_f32 %0, %1, %2" : "=v"(r.u[0]) : "v"(lo[0]), "v"(lo[1]));
  asm("v_cvt_pk_bf16_f32 %0, %1, %2" : "=v"(r.u[1]) : "v"(lo[2]), "v"(lo[3]));
  asm("v_cvt_pk_bf16_f32 %0, %1, %2" : "=v"(r.u[2]) : "v"(hi[0]), "v"(hi[1]));
  asm("v_cvt_pk_bf16_f32 %0, %1, %2" : "=v"(r.u[3]) : "v"(hi[2]), "v"(hi[3]));
  return r.s;
}
__device__ __forceinline__ s4 pk4(f32x4 v) {
  union { s4 s; unsigned u[2]; } r;
  asm("v_cvt_pk_bf16_f32 %0, %1, %2" : "=v"(r.u[0]) : "v"(v[0]), "v"(v[1]));
  asm("v_cvt_pk_bf16_f32 %0, %1, %2" : "=v"(r.u[1]) : "v"(v[2]), "v"(v[3]));
  return r.s;
}
__device__ __forceinline__ f32x4 relu4(f32x4 v) {
  f32x4 r; r[0]=fmaxf(v[0],0.f); r[1]=fmaxf(v[1],0.f);
  r[2]=fmaxf(v[2],0.f); r[3]=fmaxf(v[3],0.f); return r;
}

__global__ __launch_bounds__(256) void prep_kernel(
    const float* __restrict__ W1, const float* __restrict__ W2,
    const float* __restrict__ Wp, const float* __restrict__ b1,
    const float* __restrict__ b2, short* __restrict__ img) {
  int t = blockIdx.x * 256 + threadIdx.x;
  if (t >= IMG_SHORTS) return;
  float v = 0.f;
  if (t < F2_OFF) {
    int i = t / F1_J, r = t % F1_J;
    int blk = r >> 9, q = r & 511;
    int ln = q >> 3, e = q & 7;
    int nt = blk / 3, s = blk - nt*3;
    int n  = nt*16 + (ln & 15);
    int kp = s*32 + (ln >> 4)*8 + e;
    if (kp == 13) {
      v = (n < 77) ? b1[i*77 + n] : (n == 77 ? 1.f : 0.f);
    } else if (n < 77) {
      if (kp < 13)                  v = W1[i*5929 + kp*77 + n];
      else if (kp >= 16 && kp < 80) v = W1[i*5929 + (kp-3)*77 + n];
    }
  } else if (t < FP_OFF) {
    int u = t - F2_OFF;
    int i = u / F2_J, r = u % F2_J;
    int blk = r >> 9, q = r & 511;
    int ln = q >> 3, e = q & 7;
    int nt = blk / 3, s = blk - nt*3;
    int n  = nt*16 + (ln & 15);
    int k  = s*32 + (ln >> 4)*8 + e;
    if (k < 77)       v = W2[i*4928 + k*64 + n];
    else if (k == 77) v = b2[i*64 + n];
  } else {
    int u = t - FP_OFF;
    int blk = u >> 9, q = u & 511;
    int ln = q >> 3, e = q & 7;
    int nt = blk / 9, s = blk - nt*9;
    int n  = nt*16 + (ln & 15);
    int kp = s*32 + (ln >> 4)*8 + e;
    int j, w;
    if (kp < 216) { j = kp / 9;       w = kp % 9; }
    else          { j = (kp-216) / 3; w = 9 + (kp-216) % 3; }
    v = Wp[(j*12 + w)*64 + n];
  }
  img[t] = f2bf(v);
}

// 15 W1 fragment loads into named array (asm-pinned)
#define ISSUE_W1_INTO(ARR, JN) do { \
  unsigned long long _b = img_u + (unsigned long long)(JN)*15360ull; \
  asm volatile( \
    "global_load_dwordx4 %0, %15, %16\n"  "global_load_dwordx4 %1, %15, %16 offset:1024\n" \
    "global_load_dwordx4 %2, %15, %16 offset:2048\n" "global_load_dwordx4 %3, %15, %16 offset:3072\n" \
    "global_load_dwordx4 %4, %15, %17\n"  "global_load_dwordx4 %5, %15, %17 offset:1024\n" \
    "global_load_dwordx4 %6, %15, %17 offset:2048\n" "global_load_dwordx4 %7, %15, %17 offset:3072\n" \
    "global_load_dwordx4 %8, %15, %18\n"  "global_load_dwordx4 %9, %15, %18 offset:1024\n" \
    "global_load_dwordx4 %10, %15, %18 offset:2048\n" "global_load_dwordx4 %11, %15, %18 offset:3072\n" \
    "global_load_dwordx4 %12, %15, %19\n" "global_load_dwordx4 %13, %15, %19 offset:1024\n" \
    "global_load_dwordx4 %14, %15, %19 offset:2048\n" \
    : "=&v"(ARR[0]),"=&v"(ARR[1]),"=&v"(ARR[2]),"=&v"(ARR[3]),"=&v"(ARR[4]), \
      "=&v"(ARR[5]),"=&v"(ARR[6]),"=&v"(ARR[7]),"=&v"(ARR[8]),"=&v"(ARR[9]), \
      "=&v"(ARR[10]),"=&v"(ARR[11]),"=&v"(ARR[12]),"=&v"(ARR[13]),"=&v"(ARR[14]) \
    : "v"(voff), "s"(_b), "s"(_b+4096ull), "s"(_b+8192ull), "s"(_b+12288ull) \
    : "memory"); \
} while(0)

// 12 W2(J) x4 loads + 12 bt dword loads into named array / d regs.
// Operand map: %0-%11 bt dwords, %12-%23 W2 frags,
//   %24=aP, %25=aR, %26=voff, %27/%28/%29 = W2 sbase 0/4096/8192.
#define ISSUE_BTW2_INTO(W2A, J) do { \
  unsigned long long _b = img_u + 368640ull + (unsigned long long)(J)*12288ull; \
  asm volatile( \
    "global_load_dwordx4 %12, %26, %27\n" "global_load_dwordx4 %13, %26, %27 offset:1024\n" \
    "global_load_dwordx4 %14, %26, %27 offset:2048\n" "global_load_dwordx4 %15, %26, %27 offset:3072\n" \
    "global_load_dwordx4 %16, %26, %28\n" "global_load_dwordx4 %17, %26, %28 offset:1024\n" \
    "global_load_dwordx4 %18, %26, %28 offset:2048\n" "global_load_dwordx4 %19, %26, %28 offset:3072\n" \
    "global_load_dwordx4 %20, %26, %29\n" "global_load_dwordx4 %21, %26, %29 offset:1024\n" \
    "global_load_dwordx4 %22, %26, %29 offset:2048\n" "global_load_dwordx4 %23, %26, %29 offset:3072\n" \
    "global_load_dword %0, %24, off\n" \
    "global_load_dword %1, %24, off offset:4\n" \
    "global_load_dword %2, %24, off offset:8\n" \
    "global_load_dword %3, %24, off offset:12\n" \
    "global_load_dword %4, %24, off offset:16\n" \
    "global_load_dword %5, %24, off offset:20\n" \
    "global_load_dword %6, %24, off offset:24\n" \
    "global_load_dword %7, %24, off offset:28\n" \
    "global_load_dword %8, %24, off offset:32\n" \
    "global_load_dword %9, %25, off\n" \
    "global_load_dword %10, %25, off offset:4\n" \
    "global_load_dword %11, %25, off offset:8\n" \
    : "=&v"(d0),"=&v"(d1),"=&v"(d2),"=&v"(d3),"=&v"(d4),"=&v"(d5), \
      "=&v"(d6),"=&v"(d7),"=&v"(d8),"=&v"(d9),"=&v"(d10),"=&v"(d11), \
      "=&v"(W2A[0]),"=&v"(W2A[1]),"=&v"(W2A[2]),"=&v"(W2A[3]),"=&v"(W2A[4]),"=&v"(W2A[5]), \
      "=&v"(W2A[6]),"=&v"(W2A[7]),"=&v"(W2A[8]),"=&v"(W2A[9]),"=&v"(W2A[10]),"=&v"(W2A[11]) \
    : "v"(aP), "v"(aR), "v"(voff), \
      "s"(_b), "s"(_b+4096ull), "s"(_b+8192ull) \
    : "memory"); \
} while(0)

#define WAITV(N) do { asm volatile("s_waitcnt vmcnt(" #N ")" ::: "memory"); \
                      __builtin_amdgcn_sched_barrier(0); } while(0)

// One joint body. F1C/F2C = current weight sets (consumed); F1N/F2N = next sets
// (issued at F, BEFORE this joint's stores). ONE wait per joint:
//   C = vmcnt(16): outstanding = loads(39, older) + st(p-1)(16, newer)
//   -> retires exactly the loads; stores are NEVER waited (full joint to drain).
#define BODY(P, F1C, F2C, F1N, F2N, CW) do { \
    const int j  = ORD[P]; \
    const int ps = PSL[P]; \
    const int ss = SSL[P]; \
    const int jn = ((P)+1 < NJ) ? ORD[(P)+1] : 0; \
    WAITV(CW); \
    /* decode bt(this joint) -> btL (col13 = 1.0) */ \
    { \
      float nv = sqrtf(d9*d9 + d10*d10 + d11*d11); \
      short8 wlo = pk8((f32x4){d0,d1,d2,d3}, (f32x4){d4,d5,d6,d7}); \
      short8 whi; \
      whi[0]=sbf(d8); whi[1]=sbf(d9); whi[2]=sbf(d10); whi[3]=sbf(d11); \
      whi[4]=sbf(nv); whi[5]=(short)0x3F80; whi[6]=0; whi[7]=0; \
      *(short8*)(btL + lane*16)     = wlo; \
      *(short8*)(btL + lane*16 + 8) = whi; \
    } \
    /* D: GEMM1, fragments per-m (register diet) */ \
    _Pragma("unroll") \
    for (int m = 0; m < 4; ++m) { \
      const short* fb = featL + ps*4608 + (m*16 + cl)*72; \
      short8 a0 = (g < 2) ? *(const short8*)(btL + (m*16 + cl)*16 + g*8) \
                          : *(const short8*)(fb + (g-2)*8); \
      short8 a1 = *(const short8*)(fb + 16 + g*8); \
      short8 a2 = (g < 2) ? *(const short8*)(fb + 48 + g*8) : zz; \
      _Pragma("unroll") \
      for (int nt = 0; nt < 5; ++nt) { \
        f32x4 c = {0,0,0,0}; \
        c = MFMA(F1C[nt*3+0], a0, c); \
        c = MFMA(F1C[nt*3+1], a1, c); \
        c = MFMA(F1C[nt*3+2], a2, c); \
        *(s4*)(hL + (m*16 + cl)*80 + nt*16 + g*4) = pk4(relu4(c)); \
      } \
    } \
    /* F: issue next joint's 39 loads BEFORE this joint's stores */ \
    { \
      const unsigned long long aP = btP + (unsigned long long)(jn*36); \
      const unsigned long long aR = btR + (unsigned long long)(jn*12); \
      ISSUE_W1_INTO(F1N, jn); \
      ISSUE_BTW2_INTO(F2N, jn); \
    } \
    /* I: GEMM2, h fragments per-m — coalesced 16B nt stores + feat writes */ \
    _Pragma("unroll") \
    for (int m = 0; m < 4; ++m) { \
      const short* hb = hL + (m*16 + cl)*80; \
      short8 h0 = *(const short8*)(hb + g*8); \
      short8 h1 = *(const short8*)(hb + 32 + g*8); \
      short8 h2 = (g < 2) ? *(const short8*)(hb + 64 + g*8) : zz; \
      _Pragma("unroll") \
      for (int nt = 0; nt < 4; ++nt) { \
        f32x4 c = {0,0,0,0}; \
        c = MFMA(F2C[nt*3+0], h0, c); \
        c = MFMA(F2C[nt*3+1], h1, c); \
        c = MFMA(F2C[nt*3+2], h2, c); \
        f32x4 v = relu4(c); \
        float* o = out + (size_t)(rw0 + m*16 + cl)*1536 + (size_t)j*64 + nt*16 + g*4; \
        __builtin_nontemporal_store(v, (f32x4*)o); \
        if (ss >= 0) \
          *(s4*)(featL + ss*4608 + (m*16 + cl)*72 + nt*16 + g*4) = pk4(v); \
      } \
    } \
  } while(0)

// 256 threads = 4 waves; wave owns 64 rows (4 m-tiles) + whole tree. ZERO barriers.
// 1 WG/CU (122,880 B LDS), 1 wave/SIMD. Ping-pong weight sets; bt prefetched
// and decoded in-iteration. Stores never appear in any wait's retired set.
__global__ __launch_bounds__(256, 1) void enc_kernel(
    const float* __restrict__ pose, const float* __restrict__ rel,
    const float* __restrict__ bp,  const short* __restrict__ img,
    float* __restrict__ out) {
  __shared__ __align__(16) short lds[4*15360];       // 122,880 B -> 1 WG/CU

  const int tid  = threadIdx.x;
  const int lane = tid & 63;
  const int wv   = tid >> 6;
  short* myl   = lds + wv*15360;
  short* featL = myl;                                // 2 slots x [64][72] = 9216
  short* hL    = myl + 9216;                         // [64][80] = 5120
  short* btL   = myl + 14336;                        // [64][16] = 1024

  const int cl  = lane & 15;
  const int g   = lane >> 4;
  const int rw0 = blockIdx.x*256 + wv*64;
  const short8 zz = {0,0,0,0,0,0,0,0};
  const unsigned long long img_u  = (unsigned long long)img;
  const unsigned long long pose_u = (unsigned long long)pose;
  const unsigned long long rel_u  = (unsigned long long)rel;
  const unsigned voff = (unsigned)lane << 4;
  // bt: lane = row (64 rows)
  const unsigned long long btP = pose_u + (unsigned long long)(rw0 + lane)*864ull;
  const unsigned long long btR = rel_u  + (unsigned long long)(rw0 + lane)*288ull;

  short8 fw1a[15], fw2a[12], fw1b[15], fw2b[12];
  float d0,d1,d2,d3,d4,d5,d6,d7,d8,d9,d10,d11;

  // ---- root: WpT (A) x bonefeat (B) -> feat slot 1 (4 m-tiles, compiler loads)
#pragma unroll 1
  for (int m = 0; m < 4; ++m) {
    const float* pr = pose + (size_t)(rw0 + m*16 + cl)*216;
    const float* rr = rel  + (size_t)(rw0 + m*16 + cl)*72;
    const short8* fpg = (const short8*)(img + FP_OFF) + lane;
    short8 av[9];
#pragma unroll
    for (int s = 0; s < 9; ++s) {
      int k0 = s*32 + g*8;
      const float* sp = (k0 < 216) ? (pr + k0) : (rr + (k0 - 216));
      av[s] = pk8(*(const f32x4*)sp, *(const f32x4*)(sp + 4));
    }
#pragma unroll
    for (int nt = 0; nt < 4; ++nt) {
      f32x4 c = {0,0,0,0};
#pragma unroll
      for (int s = 0; s < 9; ++s) c = MFMA(fpg[(nt*9 + s)*64], av[s], c);
      f32x4 bb = *(const f32x4*)(bp + nt*16 + g*4);
      c[0]+=bb[0]; c[1]+=bb[1]; c[2]+=bb[2]; c[3]+=bb[3];
      *(s4*)(featL + 4608 + (m*16 + cl)*72 + nt*16 + g*4) = pk4(c);
    }
  }

  // ---- prologue F(-1): issue joint ORD[0]=0 loads (39) into set A ----
  {
    const unsigned long long aP = btP;               // jn = 0
    const unsigned long long aR = btR;
    ISSUE_W1_INTO(fw1a, 0);
    ISSUE_BTW2_INTO(fw2a, 0);
  }

  // ---- main DFS loop: 24 bodies, alternating ping-pong sets ----
  BODY(0, fw1a, fw2a, fw1b, fw2b, 0);
  BODY(1, fw1b, fw2b, fw1a, fw2a, 16);
#pragma unroll 1
  for (int q = 1; q < 12; ++q) {
    const int p = 2*q;
    BODY(p,     fw1a, fw2a, fw1b, fw2b, 16);
    BODY(p + 1, fw1b, fw2b, fw1a, fw2a, 16);
  }
}

extern "C" void kernel_launch(void* const* d_in, const int* in_sizes, int n_in,
                              void* d_out, int out_size, void* d_ws, size_t ws_size,
                              hipStream_t stream) {
  const float* pose = (const float*)d_in[0];
  const float* rel  = (const float*)d_in[1];
  const float* Wp   = (const float*)d_in[2];
  const float* bp   = (const float*)d_in[3];
  const float* W1   = (const float*)d_in[4];
  const float* b1   = (const float*)d_in[5];
  const float* W2   = (const float*)d_in[6];
  const float* b2   = (const float*)d_in[7];
  float* outp = (float*)d_out;
  short* img  = (short*)d_ws;
  const int Bn = in_sizes[0] / 216;
  prep_kernel<<<(IMG_SHORTS + 255)/256, 256, 0, stream>>>(W1, W2, Wp, b1, b2, img);
  enc_kernel<<<Bn/256, 256, 0, stream>>>(pose, rel, bp, img, outp);
}